// Round 1
// baseline (4378.009 us; speedup 1.0000x reference)
//
#include <hip/hip_runtime.h>
#include <math.h>

#define NB 8
#define CIn 32
#define COut 32
#define NIO 1024      // CIn*COut
#define NN1 256
#define NN2 256
#define NYF 129       // NN2/2+1
#define NK1 16
#define NK2 9
#define NKL 144       // NK1*NK2

typedef float2 c32;

__device__ __forceinline__ c32 cfma(c32 a, c32 b, c32 acc){
  acc.x = fmaf(a.x, b.x, acc.x); acc.x = fmaf(-a.y, b.y, acc.x);
  acc.y = fmaf(a.x, b.y, acc.y); acc.y = fmaf(a.y, b.x, acc.y);
  return acc;
}

// ---------- precompute tables ----------
__global__ void k_tw(float2* __restrict__ tw){
  int m = threadIdx.x;
  double ang = 6.283185307179586 * (double)m / 256.0;
  tw[m] = make_float2((float)cos(ang), (float)sin(ang));
}

// P1[(io*16+k)*256 + x] = 1/(i*2*pi*f1(x) - p1)
__global__ void k_p1(const float* __restrict__ p1r, const float* __restrict__ p1i, c32* __restrict__ P1){
  int idx = blockIdx.x * 256 + threadIdx.x;   // covers NIO*NK1*256
  int x = idx & 255; int iok = idx >> 8;
  float f = (x < 128) ? (float)x : (float)(x - 256);
  float a = -p1r[iok];
  float b = 6.2831853071795864f * f - p1i[iok];
  float inv = 1.0f / fmaf(a, a, b * b);
  P1[idx] = make_float2(a * inv, -b * inv);
}

// P2[(io*9+l)*129 + y] = 1/(i*2*pi*y - p2)
__global__ void k_p2(const float* __restrict__ p2r, const float* __restrict__ p2i, c32* __restrict__ P2){
  int idx = blockIdx.x * 256 + threadIdx.x;
  if (idx >= NIO * NK2 * NYF) return;
  int y = idx % NYF; int iol = idx / NYF;
  float a = -p2r[iol];
  float b = 6.2831853071795864f * (float)y - p2i[iol];
  float inv = 1.0f / fmaf(a, a, b * b);
  P2[idx] = make_float2(a * inv, -b * inv);
}

// E1[(io*16+k)*256 + z] = exp(p1 * z/256)
__global__ void k_e1(const float* __restrict__ p1r, const float* __restrict__ p1i, c32* __restrict__ E1){
  int idx = blockIdx.x * 256 + threadIdx.x;
  int z = idx & 255; int iok = idx >> 8;
  float t = (float)z * (1.0f / 256.0f);
  float er = expf(p1r[iok] * t);
  float s, c; sincosf(p1i[iok] * t, &s, &c);
  E1[idx] = make_float2(er * c, er * s);
}

// E2[(io*9+l)*256 + w] = exp(p2 * w/256)
__global__ void k_e2(const float* __restrict__ p2r, const float* __restrict__ p2i, c32* __restrict__ E2){
  int idx = blockIdx.x * 256 + threadIdx.x;
  int w = idx & 255; int iol = idx >> 8;
  float t = (float)w * (1.0f / 256.0f);
  float er = expf(p2r[iol] * t);
  float s, c; sincosf(p2i[iol] * t, &s, &c);
  E2[idx] = make_float2(er * c, er * s);
}

// R2[(io*16+k)*129 + y] = sum_l residue[io,k,l] * P2[io,l,y]
__global__ void k_R2(const float* __restrict__ rr, const float* __restrict__ ri,
                     const c32* __restrict__ P2, c32* __restrict__ R2){
  int idx = blockIdx.x * 256 + threadIdx.x;
  if (idx >= NIO * NK1 * NYF) return;
  int y = idx % NYF; int iok = idx / NYF; int io = iok >> 4;
  c32 acc = make_float2(0.0f, 0.0f);
#pragma unroll
  for (int l = 0; l < NK2; l++){
    c32 res = make_float2(rr[iok * NK2 + l], ri[iok * NK2 + l]);
    acc = cfma(res, P2[((size_t)io * NK2 + l) * NYF + y], acc);
  }
  R2[idx] = acc;
}

// ---------- forward FFT ----------
// rfft along n2 for one row; writes alpha transposed: alpha[(bi*129+y)*256 + n1], scaled 1/65536
__global__ __launch_bounds__(256) void k_rowfft(const float* __restrict__ x, const float2* __restrict__ tw,
                                                c32* __restrict__ alpha){
  __shared__ float row[256];
  __shared__ float twc[256], tws[256];
  int t = threadIdx.x;
  int bid = blockIdx.x;                      // (b*CI+i)*256 + n1
  row[t] = x[(size_t)bid * 256 + t];
  float2 w = tw[t]; twc[t] = w.x; tws[t] = w.y;
  __syncthreads();
  if (t < NYF){
    float ar = 0.0f, ai = 0.0f;
    int m = 0;
    for (int n = 0; n < 256; n++){
      float v = row[n];
      ar = fmaf(v, twc[m], ar);
      ai = fmaf(-v, tws[m], ai);
      m = (m + t) & 255;
    }
    int bi = bid >> 8, n1 = bid & 255;
    const float sc = 1.0f / 65536.0f;
    alpha[((size_t)bi * NYF + t) * 256 + n1] = make_float2(ar * sc, ai * sc);
  }
}

// complex DFT-256 along contiguous rows, in place. INV=0: e^{-i}, INV=1: e^{+i}. No scaling.
template<int INV>
__global__ __launch_bounds__(256) void k_cfft256(const float2* __restrict__ tw, c32* __restrict__ buf){
  __shared__ float rr[256], ri[256];
  __shared__ float twc[256], tws[256];
  int t = threadIdx.x;
  size_t base = (size_t)blockIdx.x * 256;
  c32 v = buf[base + t];
  rr[t] = v.x; ri[t] = v.y;
  float2 w = tw[t]; twc[t] = w.x; tws[t] = w.y;
  __syncthreads();
  float ar = 0.0f, ai = 0.0f;
  int m = 0;
  for (int n = 0; n < 256; n++){
    float c = twc[m], s = tws[m];
    float xr = rr[n], xi = ri[n];
    if (INV){
      ar = fmaf(xr, c, ar); ar = fmaf(-xi, s, ar);
      ai = fmaf(xi, c, ai); ai = fmaf( xr, s, ai);
    } else {
      ar = fmaf(xr, c, ar); ar = fmaf( xi, s, ar);
      ai = fmaf(xi, c, ai); ai = fmaf(-xr, s, ai);
    }
    m = (m + t) & 255;
  }
  buf[base + t] = make_float2(ar, ai);
}

// ---------- mode mixing: r1[b,o,y,x] = sum_i alpha[b,i,y,x] * (sum_k P1[io,k,x]*R2[io,k,y]) ----------
__global__ __launch_bounds__(256) void k_r1(const c32* __restrict__ alpha, const c32* __restrict__ P1,
                                            const c32* __restrict__ R2, c32* __restrict__ r1){
  int x = threadIdx.x;
  int bid = blockIdx.x;           // o*129 + y
  int o = bid / NYF, y = bid - o * NYF;
  c32 acc[NB];
#pragma unroll
  for (int b = 0; b < NB; b++) acc[b] = make_float2(0.0f, 0.0f);
  for (int i = 0; i < CIn; i++){
    int io = i * COut + o;
    c32 hw = make_float2(0.0f, 0.0f);
    const c32* p1p = P1 + (size_t)io * NK1 * 256 + x;
    const c32* r2p = R2 + (size_t)io * NK1 * NYF + y;
#pragma unroll
    for (int k = 0; k < NK1; k++)
      hw = cfma(p1p[(size_t)k * 256], r2p[(size_t)k * NYF], hw);
#pragma unroll
    for (int b = 0; b < NB; b++){
      c32 a = alpha[(((size_t)b * CIn + i) * NYF + y) * 256 + x];
      acc[b] = cfma(a, hw, acc[b]);
    }
  }
#pragma unroll
  for (int b = 0; b < NB; b++)
    r1[(((size_t)b * COut + o) * NYF + y) * 256 + x] = acc[b];
}

// ---------- r2[b,io,k,l] = -res[io,k,l] * sum_x P1[io,k,x] * (sum_y alpha[b,i,y,x]*P2[io,l,y]) ----------
__global__ __launch_bounds__(256) void k_r2k(const c32* __restrict__ alpha, const c32* __restrict__ P1,
                                             const c32* __restrict__ P2,
                                             const float* __restrict__ rr, const float* __restrict__ ri,
                                             c32* __restrict__ r2){
  __shared__ float Tr[NK2][257], Ti[NK2][257];
  __shared__ float P2r[NK2][NYF], P2i[NK2][NYF];
  int t = threadIdx.x;
  int bid = blockIdx.x;             // (b*CI+i)*CO + o
  int o = bid & 31; int bi = bid >> 5;   // bi = b*CI+i
  int i = bi & 31;  int b = bi >> 5;
  int io = i * COut + o;
  for (int s = t; s < NK2 * NYF; s += 256){
    c32 v = P2[(size_t)io * NK2 * NYF + s];
    int l = s / NYF, y = s - l * NYF;
    P2r[l][y] = v.x; P2i[l][y] = v.y;
  }
  __syncthreads();
  { // phase 1: T[l][x=t] = sum_y alpha[bi,y,t] * P2[l,y]
    float tr[NK2], ti[NK2];
#pragma unroll
    for (int l = 0; l < NK2; l++){ tr[l] = 0.0f; ti[l] = 0.0f; }
    const c32* ap = alpha + (size_t)bi * NYF * 256 + t;
    for (int y = 0; y < NYF; y++){
      c32 a = ap[(size_t)y * 256];
#pragma unroll
      for (int l = 0; l < NK2; l++){
        float c = P2r[l][y], s2 = P2i[l][y];
        tr[l] = fmaf(a.x, c, tr[l]); tr[l] = fmaf(-a.y, s2, tr[l]);
        ti[l] = fmaf(a.x, s2, ti[l]); ti[l] = fmaf(a.y, c, ti[l]);
      }
    }
#pragma unroll
    for (int l = 0; l < NK2; l++){ Tr[l][t] = tr[l]; Ti[l][t] = ti[l]; }
  }
  __syncthreads();
  if (t < NKL){ // phase 2
    int k = t / NK2, l = t - k * NK2;
    const c32* p1p = P1 + ((size_t)io * NK1 + k) * 256;
    float gr = 0.0f, gi = 0.0f;
#pragma unroll 4
    for (int xx = 0; xx < 256; xx++){
      c32 p = p1p[xx];
      float trv = Tr[l][xx], tiv = Ti[l][xx];
      gr = fmaf(p.x, trv, gr); gr = fmaf(-p.y, tiv, gr);
      gi = fmaf(p.x, tiv, gi); gi = fmaf( p.y, trv, gi);
    }
    float resr = rr[((size_t)io * NK1 + k) * NK2 + l];
    float resi = ri[((size_t)io * NK1 + k) * NK2 + l];
    float outr = -(resr * gr - resi * gi);
    float outi = -(resr * gi + resi * gr);
    r2[((size_t)b * NIO + io) * NKL + t] = make_float2(outr, outi);
  }
}

// ---------- irfft along y: out[b,o,z,w] = Re(S0) + (-1)^w Re(S128) + 2*sum Re(S_y e^{+i2pi yw/256}) + bias ----------
__global__ __launch_bounds__(256) void k_irow(const c32* __restrict__ s, const float* __restrict__ bias,
                                              const float2* __restrict__ tw, float* __restrict__ out){
  __shared__ float sr[NYF], si[NYF];
  __shared__ float twc[256], tws[256];
  int t = threadIdx.x;
  int bid = blockIdx.x;              // bo*256 + z
  int z = bid & 255, bo = bid >> 8;
  if (t < NYF){
    c32 v = s[((size_t)bo * NYF + t) * 256 + z];
    sr[t] = v.x; si[t] = v.y;
  }
  float2 w = tw[t]; twc[t] = w.x; tws[t] = w.y;
  __syncthreads();
  float a1 = 0.0f;
  int m = t;
  for (int y = 1; y < 128; y++){
    a1 = fmaf(sr[y], twc[m], a1);
    a1 = fmaf(-si[y], tws[m], a1);
    m = (m + t) & 255;
  }
  float val = sr[0] + ((t & 1) ? -sr[128] : sr[128]) + 2.0f * a1 + bias[bo & 31];
  out[(size_t)bid * 256 + t] = val;
}

// ---------- x2: S'[il,z]=sum_k r2*E1 ; out += Re(sum_il S' * E2) ----------
__global__ __launch_bounds__(256) void k_x2(const c32* __restrict__ r2, const c32* __restrict__ E1,
                                            const c32* __restrict__ E2, float* __restrict__ out){
  __shared__ float4 S4[288][4];
  float2* S2 = (float2*)S4;
  int t = threadIdx.x;
  int bid = blockIdx.x;              // (b*CO+o)*32 + zt
  int zt = bid & 31, bo = bid >> 5;
  int o = bo & 31, b = bo >> 5;
  int z0 = zt * 8;
  for (int sidx = t; sidx < 2304; sidx += 256){
    int z8 = sidx & 7, il = sidx >> 3;
    int i = il / NK2, l = il - i * NK2;
    int io = i * COut + o;
    const c32* r2p = r2 + ((size_t)b * NIO + io) * NKL + l;
    const c32* e1p = E1 + (size_t)io * NK1 * 256 + (z0 + z8);
    c32 acc = make_float2(0.0f, 0.0f);
#pragma unroll
    for (int k = 0; k < NK1; k++)
      acc = cfma(r2p[(size_t)k * NK2], e1p[(size_t)k * 256], acc);
    S2[il * 8 + z8] = acc;
  }
  __syncthreads();
  float acc[8];
#pragma unroll
  for (int z8 = 0; z8 < 8; z8++) acc[z8] = 0.0f;
  int w = t;
#pragma unroll 1
  for (int i = 0; i < CIn; i++){
    int io = i * COut + o;
    const c32* e2p = E2 + (size_t)io * NK2 * 256 + w;
#pragma unroll
    for (int l = 0; l < NK2; l++){
      c32 e2 = e2p[(size_t)l * 256];
      int il = i * NK2 + l;
      float4 q0 = S4[il][0], q1 = S4[il][1], q2 = S4[il][2], q3 = S4[il][3];
      acc[0] = fmaf(q0.x, e2.x, acc[0]); acc[0] = fmaf(-q0.y, e2.y, acc[0]);
      acc[1] = fmaf(q0.z, e2.x, acc[1]); acc[1] = fmaf(-q0.w, e2.y, acc[1]);
      acc[2] = fmaf(q1.x, e2.x, acc[2]); acc[2] = fmaf(-q1.y, e2.y, acc[2]);
      acc[3] = fmaf(q1.z, e2.x, acc[3]); acc[3] = fmaf(-q1.w, e2.y, acc[3]);
      acc[4] = fmaf(q2.x, e2.x, acc[4]); acc[4] = fmaf(-q2.y, e2.y, acc[4]);
      acc[5] = fmaf(q2.z, e2.x, acc[5]); acc[5] = fmaf(-q2.w, e2.y, acc[5]);
      acc[6] = fmaf(q3.x, e2.x, acc[6]); acc[6] = fmaf(-q3.y, e2.y, acc[6]);
      acc[7] = fmaf(q3.z, e2.x, acc[7]); acc[7] = fmaf(-q3.w, e2.y, acc[7]);
    }
  }
  size_t ob = ((size_t)bo * 256 + z0) * 256 + w;
#pragma unroll
  for (int z8 = 0; z8 < 8; z8++)
    out[ob + (size_t)z8 * 256] += acc[z8];
}

extern "C" void kernel_launch(void* const* d_in, const int* in_sizes, int n_in,
                              void* d_out, int out_size, void* d_ws, size_t ws_size,
                              hipStream_t stream){
  const float* x    = (const float*)d_in[0];
  const float* rr   = (const float*)d_in[1];
  const float* ri   = (const float*)d_in[2];
  const float* p1r  = (const float*)d_in[3];
  const float* p1i  = (const float*)d_in[4];
  const float* p2r  = (const float*)d_in[5];
  const float* p2i  = (const float*)d_in[6];
  const float* bias = (const float*)d_in[7];
  float* out = (float*)d_out;

  char* ws = (char*)d_ws;
  size_t off = 0;
  c32* alpha = (c32*)(ws + off); off += (size_t)NB * CIn * NYF * NN1 * sizeof(c32);   // 67.6 MB
  c32* r1    = (c32*)(ws + off); off += (size_t)NB * COut * NYF * NN1 * sizeof(c32);  // 67.6 MB
  c32* P1    = (c32*)(ws + off); off += (size_t)NIO * NK1 * NN1 * sizeof(c32);        // 33.6 MB
  c32* P2b   = (c32*)(ws + off); off += (size_t)NIO * NK2 * NYF * sizeof(c32);        //  9.5 MB
  c32* R2b   = (c32*)(ws + off); off += (size_t)NIO * NK1 * NYF * sizeof(c32);        // 16.9 MB
  c32* E1b   = (c32*)(ws + off); off += (size_t)NIO * NK1 * NN1 * sizeof(c32);        // 33.6 MB
  c32* E2b   = (c32*)(ws + off); off += (size_t)NIO * NK2 * NN2 * sizeof(c32);        // 18.9 MB
  c32* r2b   = (c32*)(ws + off); off += (size_t)NB * NIO * NKL * sizeof(c32);         //  9.4 MB
  float2* tw = (float2*)(ws + off); off += 256 * sizeof(float2);

  k_tw<<<1, 256, 0, stream>>>(tw);
  k_p1<<<NIO * NK1, 256, 0, stream>>>(p1r, p1i, P1);
  k_p2<<<(NIO * NK2 * NYF + 255) / 256, 256, 0, stream>>>(p2r, p2i, P2b);
  k_e1<<<NIO * NK1, 256, 0, stream>>>(p1r, p1i, E1b);
  k_e2<<<NIO * NK2, 256, 0, stream>>>(p2r, p2i, E2b);
  k_R2<<<(NIO * NK1 * NYF + 255) / 256, 256, 0, stream>>>(rr, ri, P2b, R2b);

  k_rowfft<<<NB * CIn * NN1, 256, 0, stream>>>(x, tw, alpha);
  k_cfft256<0><<<NB * CIn * NYF, 256, 0, stream>>>(tw, alpha);

  k_r1<<<COut * NYF, 256, 0, stream>>>(alpha, P1, R2b, r1);
  k_r2k<<<NB * CIn * COut, 256, 0, stream>>>(alpha, P1, P2b, rr, ri, r2b);

  k_cfft256<1><<<NB * COut * NYF, 256, 0, stream>>>(tw, r1);
  k_irow<<<NB * COut * NN1, 256, 0, stream>>>(r1, bias, tw, out);

  k_x2<<<NB * COut * (NN1 / 8), 256, 0, stream>>>(r2b, E1b, E2b, out);
}

// Round 2
// 1723.659 us; speedup vs baseline: 2.5400x; 2.5400x over previous
//
#include <hip/hip_runtime.h>
#include <math.h>

#define NB 8
#define CIn 32
#define COut 32
#define NIO 1024      // CIn*COut
#define NN1 256
#define NN2 256
#define NYF 129       // NN2/2+1
#define NK1 16
#define NK2 9
#define NKL 144       // NK1*NK2

typedef float2 c32;

__device__ __forceinline__ c32 cadd(c32 a, c32 b){ return make_float2(a.x+b.x, a.y+b.y); }
__device__ __forceinline__ c32 csub(c32 a, c32 b){ return make_float2(a.x-b.x, a.y-b.y); }
__device__ __forceinline__ c32 cmul(c32 a, c32 b){ return make_float2(a.x*b.x - a.y*b.y, a.x*b.y + a.y*b.x); }
__device__ __forceinline__ c32 cfma(c32 a, c32 b, c32 acc){
  acc.x = fmaf(a.x, b.x, acc.x); acc.x = fmaf(-a.y, b.y, acc.x);
  acc.y = fmaf(a.x, b.y, acc.y); acc.y = fmaf(a.y, b.x, acc.y);
  return acc;
}

// ---------------- FFT-256 via four-step radix-16 ----------------
// INV=0: e^{-2pi i}, INV=1: e^{+2pi i}. tw[m] = e^{+2pi i m/256} (exact table).
template<int INV> __device__ __forceinline__ c32 rot90(c32 a){
  return INV ? make_float2(-a.y, a.x) : make_float2(a.y, -a.x);
}
template<int INV> __device__ __forceinline__ void dft4(c32& a0, c32& a1, c32& a2, c32& a3){
  c32 t0 = cadd(a0,a2), t1 = csub(a0,a2);
  c32 t2 = cadd(a1,a3), t3 = rot90<INV>(csub(a1,a3));
  a0 = cadd(t0,t2); a1 = cadd(t1,t3); a2 = csub(t0,t2); a3 = csub(t1,t3);
}
__device__ __forceinline__ int SLOT16(int k){ return 4*(k&3) + (k>>2); }
template<int INV> __device__ __forceinline__ c32 twg(const float2* ltw, int idx){
  float2 w = ltw[idx & 255];
  return INV ? make_float2(w.x, w.y) : make_float2(w.x, -w.y);
}
// 16-pt FFT in regs; input v[n] natural order; output X16[k] lands at v[SLOT16(k)]
template<int INV> __device__ __forceinline__ void fft16r(c32 v[16], const float2* ltw){
#pragma unroll
  for (int bp = 0; bp < 4; bp++) dft4<INV>(v[bp], v[4+bp], v[8+bp], v[12+bp]);
  // v[4c+b] = F_b[c]; twiddle e^{∓2pi i (16 b c)/256}
#pragma unroll
  for (int c = 1; c < 4; c++)
#pragma unroll
    for (int bp = 1; bp < 4; bp++)
      v[4*c+bp] = cmul(v[4*c+bp], twg<INV>(ltw, 16*bp*c));
#pragma unroll
  for (int c = 0; c < 4; c++) dft4<INV>(v[4*c], v[4*c+1], v[4*c+2], v[4*c+3]);
}
// 256-pt FFT, 16 threads/row. Entry: v[a] = z[16a+b]. Exit: X[b+16d] at v[SLOT16(d)].
// tile: this row's exchange buffer, 272 c32 (16x17 padded).
template<int INV>
__device__ __forceinline__ void fft256_core(c32 v[16], int b, c32* tile, const float2* ltw){
  fft16r<INV>(v, ltw);       // v[SLOT16(c)] = F_b[c]
#pragma unroll
  for (int c = 0; c < 16; c++){
    c32 g = (c && b) ? cmul(v[SLOT16(c)], twg<INV>(ltw, b*c)) : v[SLOT16(c)];
    tile[c*17 + b] = g;      // T[c][b]
  }
  __syncthreads();
#pragma unroll
  for (int j = 0; j < 16; j++) v[j] = tile[b*17 + j];  // w[j] = G_j[s=b]
  fft16r<INV>(v, ltw);       // v[SLOT16(d)] = X[b+16d]
}

// ---------- precompute tables ----------
__global__ void k_tw(float2* __restrict__ tw){
  int m = threadIdx.x;
  double ang = 6.283185307179586 * (double)m / 256.0;
  tw[m] = make_float2((float)cos(ang), (float)sin(ang));
}

__global__ void k_p1(const float* __restrict__ p1r, const float* __restrict__ p1i, c32* __restrict__ P1){
  int idx = blockIdx.x * 256 + threadIdx.x;
  int x = idx & 255; int iok = idx >> 8;
  float f = (x < 128) ? (float)x : (float)(x - 256);
  float a = -p1r[iok];
  float b = 6.2831853071795864f * f - p1i[iok];
  float inv = 1.0f / fmaf(a, a, b * b);
  P1[idx] = make_float2(a * inv, -b * inv);
}

__global__ void k_p2(const float* __restrict__ p2r, const float* __restrict__ p2i, c32* __restrict__ P2){
  int idx = blockIdx.x * 256 + threadIdx.x;
  if (idx >= NIO * NK2 * NYF) return;
  int y = idx % NYF; int iol = idx / NYF;
  float a = -p2r[iol];
  float b = 6.2831853071795864f * (float)y - p2i[iol];
  float inv = 1.0f / fmaf(a, a, b * b);
  P2[idx] = make_float2(a * inv, -b * inv);
}

__global__ void k_e1(const float* __restrict__ p1r, const float* __restrict__ p1i, c32* __restrict__ E1){
  int idx = blockIdx.x * 256 + threadIdx.x;
  int z = idx & 255; int iok = idx >> 8;
  float t = (float)z * (1.0f / 256.0f);
  float er = expf(p1r[iok] * t);
  float s, c; sincosf(p1i[iok] * t, &s, &c);
  E1[idx] = make_float2(er * c, er * s);
}

__global__ void k_e2(const float* __restrict__ p2r, const float* __restrict__ p2i, c32* __restrict__ E2){
  int idx = blockIdx.x * 256 + threadIdx.x;
  int w = idx & 255; int iol = idx >> 8;
  float t = (float)w * (1.0f / 256.0f);
  float er = expf(p2r[iol] * t);
  float s, c; sincosf(p2i[iol] * t, &s, &c);
  E2[idx] = make_float2(er * c, er * s);
}

__global__ void k_R2(const float* __restrict__ rr, const float* __restrict__ ri,
                     const c32* __restrict__ P2, c32* __restrict__ R2){
  int idx = blockIdx.x * 256 + threadIdx.x;
  if (idx >= NIO * NK1 * NYF) return;
  int y = idx % NYF; int iok = idx / NYF; int io = iok >> 4;
  c32 acc = make_float2(0.0f, 0.0f);
#pragma unroll
  for (int l = 0; l < NK2; l++){
    c32 res = make_float2(rr[iok * NK2 + l], ri[iok * NK2 + l]);
    acc = cfma(res, P2[((size_t)io * NK2 + l) * NYF + y], acc);
  }
  R2[idx] = acc;
}

// ---------- forward: rfft along n2 (paired rows), write alpha[(bi*129+y)*256+n1], scaled 1/65536 ----------
__global__ __launch_bounds__(256) void k_fwd_y(const float* __restrict__ x, const float2* __restrict__ tw,
                                               c32* __restrict__ alpha){
  __shared__ c32 tile[16*272];
  __shared__ float2 ltw[256];
  int t = threadIdx.x;
  ltw[t] = tw[t];
  int bi = blockIdx.x >> 3;
  int n1c = (blockIdx.x & 7) << 5;
  int row = t >> 4, b = t & 15;
  const float* xe = x + ((size_t)bi * 256 + n1c + 2 * row) * 256;
  c32 v[16];
#pragma unroll
  for (int a = 0; a < 16; a++)
    v[a] = make_float2(xe[16*a + b], xe[256 + 16*a + b]);   // z = even + i*odd
  __syncthreads();
  fft256_core<0>(v, b, tile + row*272, ltw);
  __syncthreads();                       // core's tile reads done
#pragma unroll
  for (int d = 0; d < 16; d++)
    tile[row*272 + b + 16*d] = v[SLOT16(d)];   // Zbuf[row][b+16d]
  __syncthreads();
  // Hermitian unpack in place: A[h] -> slot h, B[h] -> slot 256-h ; h=0/128 packed real
  const float sc = 0.5f / 65536.0f;
#pragma unroll
  for (int j = 0; j < 8; j++){
    int item = t + 256*j;
    int h = item & 127, r2 = item >> 7;
    c32* Zb = tile + r2*272;
    if (h == 0){
      c32 z0 = Zb[0], z1 = Zb[128];
      Zb[0]   = make_float2(z0.x * (2.0f*sc), z0.y * (2.0f*sc));   // (A0, B0) real pair
      Zb[128] = make_float2(z1.x * (2.0f*sc), z1.y * (2.0f*sc));   // (A128, B128)
    } else {
      c32 zk = Zb[h], zm = Zb[256 - h];
      c32 A = make_float2(sc*(zk.x + zm.x), sc*(zk.y - zm.y));
      c32 B = make_float2(sc*(zk.y + zm.y), sc*(zm.x - zk.x));
      Zb[h] = A; Zb[256 - h] = B;
    }
  }
  __syncthreads();
  for (int j = 0; j < 17; j++){
    int idx = t + 256*j;
    if (idx >= 129*32) break;
    int y = idx >> 5, n1i = idx & 31;
    c32* Zb = tile + (n1i >> 1)*272;
    c32 val;
    if ((n1i & 1) == 0)
      val = (y == 0) ? make_float2(Zb[0].x, 0.0f)
          : (y == 128) ? make_float2(Zb[128].x, 0.0f) : Zb[y];
    else
      val = (y == 0) ? make_float2(Zb[0].y, 0.0f)
          : (y == 128) ? make_float2(Zb[128].y, 0.0f) : Zb[256 - y];
    alpha[((size_t)bi * 129 + y) * 256 + n1c + n1i] = val;
  }
}

// ---------- complex FFT-256 on contiguous rows, in place ----------
template<int INV>
__global__ __launch_bounds__(256) void k_fft_x(const float2* __restrict__ tw, c32* __restrict__ buf){
  __shared__ c32 tile[16*272];
  __shared__ float2 ltw[256];
  int t = threadIdx.x;
  ltw[t] = tw[t];
  int row = t >> 4, b = t & 15;
  c32* p = buf + ((size_t)blockIdx.x * 16 + row) * 256;
  c32 v[16];
#pragma unroll
  for (int a = 0; a < 16; a++) v[a] = p[16*a + b];
  __syncthreads();
  fft256_core<INV>(v, b, tile + row*272, ltw);
#pragma unroll
  for (int d = 0; d < 16; d++) p[b + 16*d] = v[SLOT16(d)];
}

// ---------- inverse rfft along y (paired z-columns) + bias, writes out ----------
__global__ __launch_bounds__(256) void k_inv_y(const c32* __restrict__ r1, const float* __restrict__ bias,
                                               const float2* __restrict__ tw, float* __restrict__ out){
  __shared__ c32 tile[16*272];   // SA ([129][33] = 4257 c32) aliases this
  __shared__ float2 ltw[256];
  c32* SA = tile;
  int t = threadIdx.x;
  ltw[t] = tw[t];
  int bo = blockIdx.x >> 3;
  int z0 = (blockIdx.x & 7) << 5;
  for (int j = 0; j < 17; j++){
    int idx = t + 256*j;
    if (idx >= 129*32) break;
    int y = idx >> 5, zi = idx & 31;
    SA[y*33 + zi] = r1[((size_t)bo * 129 + y) * 256 + z0 + zi];
  }
  __syncthreads();
  int p = t >> 4, b = t & 15;
  c32 v[16];
#pragma unroll
  for (int a = 0; a < 16; a++){
    int k = 16*a + b;
    int m = (k <= 128) ? k : 256 - k;
    c32 A = SA[m*33 + 2*p], B = SA[m*33 + 2*p + 1];
    if (k == 0 || k == 128)  v[a] = make_float2(A.x, B.x);
    else if (k < 128)        v[a] = make_float2(A.x - B.y, A.y + B.x);
    else                     v[a] = make_float2(A.x + B.y, B.x - A.y);
  }
  __syncthreads();     // SA consumed, tile free for exchange
  fft256_core<1>(v, b, tile + p*272, ltw);
  float bv = bias[bo & 31];
  float* o0 = out + ((size_t)bo * 256 + z0 + 2*p) * 256;
#pragma unroll
  for (int d = 0; d < 16; d++){
    c32 zz = v[SLOT16(d)];
    o0[b + 16*d]       = zz.x + bv;
    o0[256 + b + 16*d] = zz.y + bv;
  }
}

// ---------- mode mixing ----------
__global__ __launch_bounds__(256) void k_r1(const c32* __restrict__ alpha, const c32* __restrict__ P1,
                                            const c32* __restrict__ R2, c32* __restrict__ r1){
  int x = threadIdx.x;
  int bid = blockIdx.x;           // o*129 + y
  int o = bid / NYF, y = bid - o * NYF;
  c32 acc[NB];
#pragma unroll
  for (int b = 0; b < NB; b++) acc[b] = make_float2(0.0f, 0.0f);
  for (int i = 0; i < CIn; i++){
    int io = i * COut + o;
    c32 hw = make_float2(0.0f, 0.0f);
    const c32* p1p = P1 + (size_t)io * NK1 * 256 + x;
    const c32* r2p = R2 + (size_t)io * NK1 * NYF + y;
#pragma unroll
    for (int k = 0; k < NK1; k++)
      hw = cfma(p1p[(size_t)k * 256], r2p[(size_t)k * NYF], hw);
#pragma unroll
    for (int b = 0; b < NB; b++){
      c32 a = alpha[(((size_t)b * CIn + i) * NYF + y) * 256 + x];
      acc[b] = cfma(a, hw, acc[b]);
    }
  }
#pragma unroll
  for (int b = 0; b < NB; b++)
    r1[(((size_t)b * COut + o) * NYF + y) * 256 + x] = acc[b];
}

__global__ __launch_bounds__(256) void k_r2k(const c32* __restrict__ alpha, const c32* __restrict__ P1,
                                             const c32* __restrict__ P2,
                                             const float* __restrict__ rr, const float* __restrict__ ri,
                                             c32* __restrict__ r2){
  __shared__ float Tr[NK2][257], Ti[NK2][257];
  __shared__ float P2r[NK2][NYF], P2i[NK2][NYF];
  int t = threadIdx.x;
  int bid = blockIdx.x;
  int o = bid & 31; int bi = bid >> 5;
  int i = bi & 31;  int b = bi >> 5;
  int io = i * COut + o;
  for (int s = t; s < NK2 * NYF; s += 256){
    c32 v = P2[(size_t)io * NK2 * NYF + s];
    int l = s / NYF, y = s - l * NYF;
    P2r[l][y] = v.x; P2i[l][y] = v.y;
  }
  __syncthreads();
  {
    float tr[NK2], ti[NK2];
#pragma unroll
    for (int l = 0; l < NK2; l++){ tr[l] = 0.0f; ti[l] = 0.0f; }
    const c32* ap = alpha + (size_t)bi * NYF * 256 + t;
    for (int y = 0; y < NYF; y++){
      c32 a = ap[(size_t)y * 256];
#pragma unroll
      for (int l = 0; l < NK2; l++){
        float c = P2r[l][y], s2 = P2i[l][y];
        tr[l] = fmaf(a.x, c, tr[l]); tr[l] = fmaf(-a.y, s2, tr[l]);
        ti[l] = fmaf(a.x, s2, ti[l]); ti[l] = fmaf(a.y, c, ti[l]);
      }
    }
#pragma unroll
    for (int l = 0; l < NK2; l++){ Tr[l][t] = tr[l]; Ti[l][t] = ti[l]; }
  }
  __syncthreads();
  if (t < NKL){
    int k = t / NK2, l = t - k * NK2;
    const c32* p1p = P1 + ((size_t)io * NK1 + k) * 256;
    float gr = 0.0f, gi = 0.0f;
#pragma unroll 4
    for (int xx = 0; xx < 256; xx++){
      c32 p = p1p[xx];
      float trv = Tr[l][xx], tiv = Ti[l][xx];
      gr = fmaf(p.x, trv, gr); gr = fmaf(-p.y, tiv, gr);
      gi = fmaf(p.x, tiv, gi); gi = fmaf( p.y, trv, gi);
    }
    float resr = rr[((size_t)io * NK1 + k) * NK2 + l];
    float resi = ri[((size_t)io * NK1 + k) * NK2 + l];
    float outr = -(resr * gr - resi * gi);
    float outi = -(resr * gi + resi * gr);
    r2[((size_t)b * NIO + io) * NKL + t] = make_float2(outr, outi);
  }
}

__global__ __launch_bounds__(256) void k_x2(const c32* __restrict__ r2, const c32* __restrict__ E1,
                                            const c32* __restrict__ E2, float* __restrict__ out){
  __shared__ float4 S4[288][4];
  float2* S2 = (float2*)S4;
  int t = threadIdx.x;
  int bid = blockIdx.x;
  int zt = bid & 31, bo = bid >> 5;
  int o = bo & 31, b = bo >> 5;
  int z0 = zt * 8;
  for (int sidx = t; sidx < 2304; sidx += 256){
    int z8 = sidx & 7, il = sidx >> 3;
    int i = il / NK2, l = il - i * NK2;
    int io = i * COut + o;
    const c32* r2p = r2 + ((size_t)b * NIO + io) * NKL + l;
    const c32* e1p = E1 + (size_t)io * NK1 * 256 + (z0 + z8);
    c32 acc = make_float2(0.0f, 0.0f);
#pragma unroll
    for (int k = 0; k < NK1; k++)
      acc = cfma(r2p[(size_t)k * NK2], e1p[(size_t)k * 256], acc);
    S2[il * 8 + z8] = acc;
  }
  __syncthreads();
  float acc[8];
#pragma unroll
  for (int z8 = 0; z8 < 8; z8++) acc[z8] = 0.0f;
  int w = t;
#pragma unroll 1
  for (int i = 0; i < CIn; i++){
    int io = i * COut + o;
    const c32* e2p = E2 + (size_t)io * NK2 * 256 + w;
#pragma unroll
    for (int l = 0; l < NK2; l++){
      c32 e2 = e2p[(size_t)l * 256];
      int il = i * NK2 + l;
      float4 q0 = S4[il][0], q1 = S4[il][1], q2 = S4[il][2], q3 = S4[il][3];
      acc[0] = fmaf(q0.x, e2.x, acc[0]); acc[0] = fmaf(-q0.y, e2.y, acc[0]);
      acc[1] = fmaf(q0.z, e2.x, acc[1]); acc[1] = fmaf(-q0.w, e2.y, acc[1]);
      acc[2] = fmaf(q1.x, e2.x, acc[2]); acc[2] = fmaf(-q1.y, e2.y, acc[2]);
      acc[3] = fmaf(q1.z, e2.x, acc[3]); acc[3] = fmaf(-q1.w, e2.y, acc[3]);
      acc[4] = fmaf(q2.x, e2.x, acc[4]); acc[4] = fmaf(-q2.y, e2.y, acc[4]);
      acc[5] = fmaf(q2.z, e2.x, acc[5]); acc[5] = fmaf(-q2.w, e2.y, acc[5]);
      acc[6] = fmaf(q3.x, e2.x, acc[6]); acc[6] = fmaf(-q3.y, e2.y, acc[6]);
      acc[7] = fmaf(q3.z, e2.x, acc[7]); acc[7] = fmaf(-q3.w, e2.y, acc[7]);
    }
  }
  size_t ob = ((size_t)bo * 256 + z0) * 256 + w;
#pragma unroll
  for (int z8 = 0; z8 < 8; z8++)
    out[ob + (size_t)z8 * 256] += acc[z8];
}

extern "C" void kernel_launch(void* const* d_in, const int* in_sizes, int n_in,
                              void* d_out, int out_size, void* d_ws, size_t ws_size,
                              hipStream_t stream){
  const float* x    = (const float*)d_in[0];
  const float* rr   = (const float*)d_in[1];
  const float* ri   = (const float*)d_in[2];
  const float* p1r  = (const float*)d_in[3];
  const float* p1i  = (const float*)d_in[4];
  const float* p2r  = (const float*)d_in[5];
  const float* p2i  = (const float*)d_in[6];
  const float* bias = (const float*)d_in[7];
  float* out = (float*)d_out;

  char* ws = (char*)d_ws;
  size_t off = 0;
  c32* alpha = (c32*)(ws + off); off += (size_t)NB * CIn * NYF * NN1 * sizeof(c32);
  c32* r1b   = (c32*)(ws + off); off += (size_t)NB * COut * NYF * NN1 * sizeof(c32);
  c32* P1    = (c32*)(ws + off); off += (size_t)NIO * NK1 * NN1 * sizeof(c32);
  c32* P2b   = (c32*)(ws + off); off += (size_t)NIO * NK2 * NYF * sizeof(c32);
  c32* R2b   = (c32*)(ws + off); off += (size_t)NIO * NK1 * NYF * sizeof(c32);
  c32* E1b   = (c32*)(ws + off); off += (size_t)NIO * NK1 * NN1 * sizeof(c32);
  c32* E2b   = (c32*)(ws + off); off += (size_t)NIO * NK2 * NN2 * sizeof(c32);
  c32* r2b   = (c32*)(ws + off); off += (size_t)NB * NIO * NKL * sizeof(c32);
  float2* tw = (float2*)(ws + off); off += 256 * sizeof(float2);

  k_tw<<<1, 256, 0, stream>>>(tw);
  k_p1<<<NIO * NK1, 256, 0, stream>>>(p1r, p1i, P1);
  k_p2<<<(NIO * NK2 * NYF + 255) / 256, 256, 0, stream>>>(p2r, p2i, P2b);
  k_e1<<<NIO * NK1, 256, 0, stream>>>(p1r, p1i, E1b);
  k_e2<<<NIO * NK2, 256, 0, stream>>>(p2r, p2i, E2b);
  k_R2<<<(NIO * NK1 * NYF + 255) / 256, 256, 0, stream>>>(rr, ri, P2b, R2b);

  k_fwd_y<<<NB * CIn * 8, 256, 0, stream>>>(x, tw, alpha);            // 2048 blocks
  k_fft_x<0><<<NB * CIn * NYF / 16, 256, 0, stream>>>(tw, alpha);     // 2064 blocks

  k_r1<<<COut * NYF, 256, 0, stream>>>(alpha, P1, R2b, r1b);
  k_r2k<<<NB * CIn * COut, 256, 0, stream>>>(alpha, P1, P2b, rr, ri, r2b);

  k_fft_x<1><<<NB * COut * NYF / 16, 256, 0, stream>>>(tw, r1b);      // 2064 blocks
  k_inv_y<<<NB * COut * 8, 256, 0, stream>>>(r1b, bias, tw, out);     // 2048 blocks

  k_x2<<<NB * COut * (NN1 / 8), 256, 0, stream>>>(r2b, E1b, E2b, out);
}